// Round 4
// baseline (244.953 us; speedup 1.0000x reference)
//
#include <hip/hip_runtime.h>

// shift op: out[b, g*32+c, h, w] = x[b, g*32+c, h+dh, w+dw] (zero outside),
// groups g=0..7 with offsets; channels 256..287 stay zero.
// (32, 288, 64, 64) fp32. Pure memory-bound shuffle: 285 MB total -> ~45us floor.
//
// v4: persistent grid-stride version of v1. Same per-slab work (16-row slab,
// one dwordx4 load + one cross-lane __shfl + one dwordx4 store per thread,
// nt on both streams) and same slab ordering (consecutive active blocks write
// consecutive 4KB slabs), but grid = 2048 (exactly resident: 8 blk/CU) and an
// explicit 2-stage pipeline: slab i+1's load is issued BEFORE slab i's
// vmcnt wait, so each wave keeps 2 loads in flight steady-state and the
// per-block setup (kernarg, index math, endpgm) is amortized 18x.
// Zero cases (g==8, OOB row) are staged as a=0 with the same store path:
// rows are uniform within 16-lane groups, so shfl of zeros yields zeros.
// [v2 post-mortem: MLP helped nothing when the geometry also changed; this
//  keeps v1 geometry exactly. v3b: nt hints -2us, kept.]

#define CC  288
#define HH  64
#define WW  64
#define NB  (32 * CC * 4)   // 36864 slabs
#define GRID 2048           // 8 blocks/CU * 256 CU = exactly resident

typedef float v4f __attribute__((ext_vector_type(4)));

__global__ __launch_bounds__(256) void shift_kernel(const float* __restrict__ x,
                                                    float* __restrict__ out) {
    const int t    = threadIdx.x;            // 0..255
    const int w0   = (t & 15) << 2;          // 0,4,...,60
    const int rr   = t >> 4;                 // row within 16-row slab
    const int lane = t & 63;

    // stage slab b: compute dst, dw, and issue the (predicated) nt load
    auto stage = [&](int b, v4f& A, int& DW, float*& D) {
        const int plane   = b >> 2;          // b*C + c
        const int quarter = b & 3;
        const int c       = plane % CC;
        const int g       = c >> 5;
        const int h       = (quarter << 4) + rr;
        D = out + (size_t)plane * (HH * WW) + h * WW + w0;
        if (g >= 8) {                        // group 8: stays zero
            A = (v4f){0.f, 0.f, 0.f, 0.f};
            DW = 0;
            return;
        }
        // offsets: g0(-1,0) g1(1,0) g2(0,-1) g3(0,1) g4(-1,-1) g5(-1,1) g6(1,-1) g7(1,1)
        const int dh = (int)((0x22001120u >> (g * 4)) & 0xFu) - 1;
        DW           = (int)((0x20202011u >> (g * 4)) & 0xFu) - 1;
        const int hs = h + dh;
        if ((unsigned)hs >= (unsigned)HH) {  // OOB row: zero (row-uniform per
            A = (v4f){0.f, 0.f, 0.f, 0.f};   // 16-lane group -> shfl path safe)
            return;
        }
        A = __builtin_nontemporal_load(
                (const v4f*)(x + (size_t)plane * (HH * WW) + hs * WW + w0));
    };

    // combine + nt store (dw is wave-uniform: whole block shares one plane)
    auto process = [&](v4f A, int DW, float* D) {
        v4f v;
        if (DW == 0) {
            v = A;
        } else if (DW == 1) {
            // out[w] = row[w+1]; row[w0+4] == lane+1's A.x (16 lanes per row)
            float nx = __shfl(A.x, (lane + 1) & 63);
            v.x = A.y; v.y = A.z; v.z = A.w;
            v.w = (w0 == 60) ? 0.f : nx;     // row edge -> zero
        } else {
            // out[w] = row[w-1]; row[w0-1] == lane-1's A.w
            float pw = __shfl(A.w, (lane - 1) & 63);
            v.x = (w0 == 0) ? 0.f : pw;
            v.y = A.x; v.z = A.y; v.w = A.z;
        }
        __builtin_nontemporal_store(v, (v4f*)D);
    };

    // 2-stage software pipeline over slabs blockIdx.x, +GRID, ... (18 iters)
    int b = blockIdx.x;
    v4f a0; int d0; float* p0;
    stage(b, a0, d0, p0);
    for (int nb = b + GRID; nb < NB; nb += GRID) {
        v4f a1; int d1; float* p1;
        stage(nb, a1, d1, p1);               // issue next load first
        process(a0, d0, p0);                 // then wait/shuffle/store current
        a0 = a1; d0 = d1; p0 = p1;
    }
    process(a0, d0, p0);
}

extern "C" void kernel_launch(void* const* d_in, const int* in_sizes, int n_in,
                              void* d_out, int out_size, void* d_ws, size_t ws_size,
                              hipStream_t stream) {
    const float* x = (const float*)d_in[0];
    float* out = (float*)d_out;
    shift_kernel<<<dim3(GRID), dim3(256), 0, stream>>>(x, out);
}